// Round 11
// baseline (342.678 us; speedup 1.0000x reference)
//
#include <hip/hip_runtime.h>
#include <hip/hip_bf16.h>

typedef __attribute__((ext_vector_type(8))) short bf16x8;
typedef __attribute__((ext_vector_type(16))) float f32x16;
typedef __attribute__((ext_vector_type(4))) unsigned int u32x4;
typedef __attribute__((ext_vector_type(4))) float f32x4;

#define CIN   64
#define KOUT  64
#define HH_   128
#define WW_   128
#define HW    (HH_ * WW_)

__device__ __forceinline__ unsigned short f2bf(float f) {
    return __builtin_bit_cast(unsigned short, __float2bfloat16(f));
}

// ---------------- weights prepack: [kc][tap][hi][ko][8] (A-frag order) ------
__global__ __launch_bounds__(256) void prepack(const float* __restrict__ wgt,
                                               unsigned short* __restrict__ wpk) {
    int i = blockIdx.x * 256 + threadIdx.x;
    if (i >= KOUT * CIN * 9) return;
    int tap = i % 9, rem = i / 9;
    int c = rem % CIN, ko = rem / CIN;
    float v = wgt[((size_t)ko * CIN + c) * 9 + tap];
    int cc = c >> 4, hi = (c >> 3) & 1, j = c & 7;
    wpk[((((size_t)cc * 9 + tap) * 2 + hi) * KOUT + ko) * 8 + j] = f2bf(v);
}

// ---------------- x transpose: f32 NCHW -> bf16 [n][h][wp 0..129][c64] ------
// wp = w+1; columns wp=0 and wp=129 zeroed (w-halo).
__global__ __launch_bounds__(256) void xpose(const float* __restrict__ x,
                                             unsigned short* __restrict__ xt) {
    __shared__ float lds[128][65];
    const int t = threadIdx.x;
    const int h = blockIdx.x;
    const int n = blockIdx.y;

    // phase 1: read 64c x 128w f32 plane-row (L1-friendly), store to LDS
    const int c = t >> 2, wq = t & 3;
    const float* xp = x + ((size_t)(n * 64 + c) * 128 + h) * 128 + wq * 32;
    #pragma unroll
    for (int j = 0; j < 8; ++j) {
        f32x4 v = *reinterpret_cast<const f32x4*>(xp + j * 4);
        #pragma unroll
        for (int e = 0; e < 4; ++e) lds[wq * 32 + j * 4 + e][c] = v[e];
    }
    __syncthreads();

    // phase 2: per (w,half): gather 32 c, cvt+pack, 64B contiguous store
    const int w = t >> 1, half = t & 1;
    u32x4 o[4];
    #pragma unroll
    for (int q = 0; q < 16; ++q) {
        unsigned lo = f2bf(lds[w][half * 32 + 2 * q]);
        unsigned hi2 = f2bf(lds[w][half * 32 + 2 * q + 1]);
        o[q >> 2][q & 3] = lo | (hi2 << 16);
    }
    unsigned short* op = xt + ((size_t)(n * 128 + h) * 130 + (w + 1)) * 64 + half * 32;
    #pragma unroll
    for (int q4 = 0; q4 < 4; ++q4)
        *reinterpret_cast<u32x4*>(op + q4 * 8) = o[q4];

    // zero the w-halo columns wp=0 and wp=129
    if (t < 16) {
        const int wpsel = t >> 3, g = t & 7;
        u32x4 z = {0u, 0u, 0u, 0u};
        *reinterpret_cast<u32x4*>(
            xt + ((size_t)(n * 128 + h) * 130 + wpsel * 129) * 64 + g * 8) = z;
    }
}

// ---------------- main conv: no LDS, no barriers, direct NHWC B-frags -------
__global__ __launch_bounds__(256, 2) void conv_nhwc(
    const unsigned short* __restrict__ xt, const unsigned short* __restrict__ wpk,
    const float* __restrict__ bias, float* __restrict__ out)
{
    const int tid  = threadIdx.x;
    const int lane = tid & 63;
    const int wv   = tid >> 6;     // 0..3 = output row within tile
    const int l31  = lane & 31;
    const int hi   = lane >> 5;

    // bijective XCD swizzle (1024 % 8 == 0)
    const int b    = blockIdx.x;
    const int work = (b & 7) * 128 + (b >> 3);
    const int ht   = work & 31;
    const int n    = work >> 5;
    const int h0   = ht * 4;

    f32x16 acc[2][4];
    #pragma unroll
    for (int mt = 0; mt < 2; ++mt)
        #pragma unroll
        for (int nt = 0; nt < 4; ++nt)
            #pragma unroll
            for (int p = 0; p < 16; ++p) acc[mt][nt][p] = 0.f;

    #pragma unroll
    for (int r = 0; r < 3; ++r) {
        const int hh = h0 + wv + r - 1;
        if ((unsigned)hh >= (unsigned)HH_) continue;   // wave-uniform skip (adds 0)
        // per-lane base: row hh, col l31, c-octet hi
        const unsigned short* bx =
            xt + ((size_t)(n * 128 + hh) * 130 + l31) * 64 + hi * 8;
        #pragma unroll
        for (int kc = 0; kc < 4; ++kc) {
            #pragma unroll
            for (int s = 0; s < 3; ++s) {
                const int tap = r * 3 + s;
                const size_t wbase = (((size_t)kc * 9 + tap) * 2 + hi) * KOUT;
                bf16x8 af0 = *reinterpret_cast<const bf16x8*>(&wpk[(wbase + l31) * 8]);
                bf16x8 af1 = *reinterpret_cast<const bf16x8*>(&wpk[(wbase + 32 + l31) * 8]);
                #pragma unroll
                for (int nt = 0; nt < 4; ++nt) {
                    bf16x8 bv = *reinterpret_cast<const bf16x8*>(
                        bx + (size_t)(nt * 32 + s) * 64 + kc * 16);
                    acc[0][nt] = __builtin_amdgcn_mfma_f32_32x32x16_bf16(
                        af0, bv, acc[0][nt], 0, 0, 0);
                    acc[1][nt] = __builtin_amdgcn_mfma_f32_32x32x16_bf16(
                        af1, bv, acc[1][nt], 0, 0, 0);
                }
            }
        }
    }

    // epilogue: bias + coalesced nontemporal stores
    float* ob = out + (size_t)n * KOUT * HW + (size_t)(h0 + wv) * WW_;
    #pragma unroll
    for (int mt = 0; mt < 2; ++mt)
        #pragma unroll
        for (int p = 0; p < 16; ++p) {
            const int ko = mt * 32 + (p & 3) + 8 * (p >> 2) + 4 * hi;
            const float bv = bias[ko];
            #pragma unroll
            for (int nt = 0; nt < 4; ++nt)
                __builtin_nontemporal_store(acc[mt][nt][p] + bv,
                    &ob[(size_t)ko * HW + nt * 32 + l31]);
        }
}

// ---------------- fallback (r9 kernel, verbatim): used if ws too small ------
__global__ __launch_bounds__(256, 2) void conv_mfma(
    const float* __restrict__ x, const unsigned short* __restrict__ wpk,
    const float* __restrict__ bias, float* __restrict__ out)
{
    __shared__ __align__(16) unsigned short xs[2][6][130][16];
    const int tid  = threadIdx.x;
    const int lane = tid & 63;
    const int wv   = tid >> 6;
    const int l31  = lane & 31;
    const int hi   = lane >> 5;
    const int b    = blockIdx.x;
    const int work = (b & 7) * 128 + (b >> 3);
    const int ht   = work & 31;
    const int n    = work >> 5;
    const int h0   = ht * 4;

    if (tid < 48) {
        int i = tid;
        int bufi = i / 24; i -= bufi * 24;
        int r = i >> 2, cs = (i >> 1) & 1, g = i & 1;
        u32x4 z = {0u, 0u, 0u, 0u};
        *reinterpret_cast<u32x4*>(&xs[bufi][r][cs ? 129 : 0][g * 8]) = z;
    }
    f32x16 acc[2][4];
    #pragma unroll
    for (int mt = 0; mt < 2; ++mt)
        #pragma unroll
        for (int p = 0; p < 16; ++p) {
            float bv = bias[mt * 32 + (p & 3) + 8 * (p >> 2) + 4 * hi];
            #pragma unroll
            for (int nt = 0; nt < 4; ++nt) acc[mt][nt][p] = bv;
        }
    const float* xb   = x + (size_t)n * CIN * HW;
    const int    sch  = tid & 1;
    const int    scol = tid >> 1;
    int  hh[6]; bool okr[6];
    #pragma unroll
    for (int r6 = 0; r6 < 6; ++r6) {
        hh[r6]  = h0 - 1 + r6;
        okr[r6] = (hh[r6] >= 0) && (hh[r6] < HH_);
    }
    const int sgp = sch ^ (((scol + 1) >> 2) & 1);
    float rx[6][8];
    auto ISSUE = [&](int cc) {
        #pragma unroll
        for (int r6 = 0; r6 < 6; ++r6)
            #pragma unroll
            for (int e = 0; e < 8; ++e)
                rx[r6][e] = okr[r6]
                    ? xb[(size_t)(cc * 16 + sch * 8 + e) * HW + hh[r6] * WW_ + scol]
                    : 0.f;
    };
    auto WRITE = [&](int bufi) {
        #pragma unroll
        for (int r6 = 0; r6 < 6; ++r6) {
            u32x4 u;
            #pragma unroll
            for (int q = 0; q < 4; ++q)
                u[q] = (unsigned)f2bf(rx[r6][2 * q]) |
                       ((unsigned)f2bf(rx[r6][2 * q + 1]) << 16);
            *reinterpret_cast<u32x4*>(&xs[bufi][r6][scol + 1][sgp * 8]) = u;
        }
    };
    auto ALOAD1 = [&](int cc, int tap, bf16x8* dst) {
        const size_t wbase = (((size_t)cc * 9 + tap) * 2 + hi) * KOUT;
        dst[0] = *reinterpret_cast<const bf16x8*>(&wpk[(wbase + l31) * 8]);
        dst[1] = *reinterpret_cast<const bf16x8*>(&wpk[(wbase + 32 + l31) * 8]);
    };
    ISSUE(0);
    #pragma unroll
    for (int cc = 0; cc < 4; ++cc) {
        WRITE(cc & 1);
        if (cc < 3) ISSUE(cc + 1);
        bf16x8 afr[2][2];
        ALOAD1(cc, 0, afr[0]);
        ALOAD1(cc, 1, afr[1]);
        asm volatile("s_waitcnt lgkmcnt(0)" ::: "memory");
        __builtin_amdgcn_s_barrier();
        asm volatile("" ::: "memory");
        __builtin_amdgcn_s_setprio(1);
        #pragma unroll
        for (int tap = 0; tap < 9; ++tap) {
            const int r = tap / 3, s = tap % 3;
            bf16x8 a0 = afr[tap & 1][0];
            bf16x8 a1 = afr[tap & 1][1];
            if (tap + 2 < 9) ALOAD1(cc, tap + 2, afr[tap & 1]);
            #pragma unroll
            for (int nt = 0; nt < 4; ++nt) {
                const int lcol = nt * 32 + l31 + s;
                const int gp   = hi ^ ((lcol >> 2) & 1);
                bf16x8 bv = *reinterpret_cast<const bf16x8*>(
                    &xs[cc & 1][wv + r][lcol][gp * 8]);
                acc[0][nt] = __builtin_amdgcn_mfma_f32_32x32x16_bf16(
                    a0, bv, acc[0][nt], 0, 0, 0);
                acc[1][nt] = __builtin_amdgcn_mfma_f32_32x32x16_bf16(
                    a1, bv, acc[1][nt], 0, 0, 0);
            }
        }
        __builtin_amdgcn_s_setprio(0);
    }
    float* ob = out + (size_t)n * KOUT * HW + (size_t)(h0 + wv) * WW_;
    #pragma unroll
    for (int mt = 0; mt < 2; ++mt)
        #pragma unroll
        for (int p = 0; p < 16; ++p) {
            const int ko = mt * 32 + (p & 3) + 8 * (p >> 2) + 4 * hi;
            #pragma unroll
            for (int nt = 0; nt < 4; ++nt)
                __builtin_nontemporal_store(acc[mt][nt][p],
                    &ob[(size_t)ko * HW + nt * 32 + l31]);
        }
}

extern "C" void kernel_launch(void* const* d_in, const int* in_sizes, int n_in,
                              void* d_out, int out_size, void* d_ws, size_t ws_size,
                              hipStream_t stream) {
    const float* x    = (const float*)d_in[0];
    const float* wgt  = (const float*)d_in[1];
    const float* bias = (const float*)d_in[2];
    float* out        = (float*)d_out;

    unsigned short* wpk = (unsigned short*)d_ws;                       // 73728 B
    unsigned short* xt  = (unsigned short*)((char*)d_ws + 131072);     // NHWC bf16
    const size_t need = 131072 + (size_t)32 * 128 * 130 * 64 * 2;      // ~136.4 MB

    prepack<<<dim3(144), dim3(256), 0, stream>>>(wgt, wpk);
    if (ws_size >= need) {
        xpose<<<dim3(128, 32), dim3(256), 0, stream>>>(x, xt);
        conv_nhwc<<<dim3(1024), dim3(256), 0, stream>>>(xt, wpk, bias, out);
    } else {
        conv_mfma<<<dim3(1024), dim3(256), 0, stream>>>(x, wpk, bias, out);
    }
}

// Round 12
// 71.681 us; speedup vs baseline: 4.7806x; 4.7806x over previous
//
#include <hip/hip_runtime.h>
#include <hip/hip_bf16.h>

typedef __attribute__((ext_vector_type(8))) short bf16x8;
typedef __attribute__((ext_vector_type(16))) float f32x16;
typedef __attribute__((ext_vector_type(4))) unsigned int u32x4;

#define CIN   64
#define KOUT  64
#define HH_   128
#define WW_   128
#define HW    (HH_ * WW_)

__device__ __forceinline__ unsigned short f2bf(float f) {
    return __builtin_bit_cast(unsigned short, __float2bfloat16(f));
}

// wpk layout: [cc][tap][hi][ko][j]  (A-fragment order for mfma_32x32x16_bf16)
__global__ __launch_bounds__(256) void prepack(const float* __restrict__ wgt,
                                               unsigned short* __restrict__ wpk) {
    int i = blockIdx.x * 256 + threadIdx.x;
    if (i >= KOUT * CIN * 9) return;
    int tap = i % 9, rem = i / 9;
    int c = rem % CIN, ko = rem / CIN;
    float v = wgt[((size_t)ko * CIN + c) * 9 + tap];
    int cc = c >> 4, hi = (c >> 3) & 1, j = c & 7;
    wpk[((((size_t)cc * 9 + tap) * 2 + hi) * KOUT + ko) * 8 + j] = f2bf(v);
}

__global__ __launch_bounds__(256, 2) void conv_mfma(
    const float* __restrict__ x, const unsigned short* __restrict__ wpk,
    const float* __restrict__ bias, float* __restrict__ out)
{
    // double-buffered x-tile: [buf][row 0..5][col 0..129][c16]  (49920 B)
    __shared__ __align__(16) unsigned short xs[2][6][130][16];

    const int tid  = threadIdx.x;
    const int lane = tid & 63;
    const int wv   = tid >> 6;     // 0..3 = output row within tile
    const int l31  = lane & 31;
    const int hi   = lane >> 5;

    // bijective XCD swizzle (1024 % 8 == 0)
    const int b    = blockIdx.x;
    const int work = (b & 7) * 128 + (b >> 3);
    const int ht   = work & 31;
    const int n    = work >> 5;
    const int h0   = ht * 4;

    // zero w-halo columns (both buffers, 6 rows, 2 c-halves)
    if (tid < 48) {
        int i = tid;
        int bufi = i / 24; i -= bufi * 24;
        int r = i >> 2, cs = (i >> 1) & 1, g = i & 1;
        u32x4 z = {0u, 0u, 0u, 0u};
        *reinterpret_cast<u32x4*>(&xs[bufi][r][cs ? 129 : 0][g * 8]) = z;
    }

    // acc init with bias: D row(M=kout) = (p&3)+8*(p>>2)+4*hi, col(N)=l31
    f32x16 acc[2][4];
    #pragma unroll
    for (int mt = 0; mt < 2; ++mt)
        #pragma unroll
        for (int p = 0; p < 16; ++p) {
            float bv = bias[mt * 32 + (p & 3) + 8 * (p >> 2) + 4 * hi];
            #pragma unroll
            for (int nt = 0; nt < 4; ++nt) acc[mt][nt][p] = bv;
        }

    const float* xb   = x + (size_t)n * CIN * HW;
    const int    sch  = tid & 1;    // c-half this thread stages
    const int    scol = tid >> 1;   // 0..127
    int  hh[6]; bool okr[6];
    #pragma unroll
    for (int r6 = 0; r6 < 6; ++r6) {
        hh[r6]  = h0 - 1 + r6;
        okr[r6] = (hh[r6] >= 0) && (hh[r6] < HH_);
    }
    const int sgp = sch ^ (((scol + 1) >> 2) & 1);  // swizzled c-slot for writes

    float rx[6][8];  // staged x (f32) for one chunk, live across the barrier

    auto ISSUE = [&](int cc) {
        #pragma unroll
        for (int r6 = 0; r6 < 6; ++r6)
            #pragma unroll
            for (int e = 0; e < 8; ++e)
                rx[r6][e] = okr[r6]
                    ? xb[(size_t)(cc * 16 + sch * 8 + e) * HW + hh[r6] * WW_ + scol]
                    : 0.f;
    };
    auto WRITE = [&](int bufi) {
        #pragma unroll
        for (int r6 = 0; r6 < 6; ++r6) {
            u32x4 u;
            #pragma unroll
            for (int q = 0; q < 4; ++q)
                u[q] = (unsigned)f2bf(rx[r6][2 * q]) |
                       ((unsigned)f2bf(rx[r6][2 * q + 1]) << 16);
            *reinterpret_cast<u32x4*>(&xs[bufi][r6][scol + 1][sgp * 8]) = u;
        }
    };
    auto ALOAD1 = [&](int cc, int tap, bf16x8* dst) {
        const size_t wbase = (((size_t)cc * 9 + tap) * 2 + hi) * KOUT;
        dst[0] = *reinterpret_cast<const bf16x8*>(&wpk[(wbase + l31) * 8]);
        dst[1] = *reinterpret_cast<const bf16x8*>(&wpk[(wbase + 32 + l31) * 8]);
    };

    // pipeline: WRITE(cc) | ALOAD taps 0-1 (first in VMEM queue) |
    //           ISSUE(cc+1) | lgkmcnt(0)+s_barrier (vmcnt NOT drained) |
    //           COMPUTE(cc).  Rolled loop: one copy of the chunk body.
    ISSUE(0);
    #pragma unroll 1
    for (int cc = 0; cc < 4; ++cc) {
        WRITE(cc & 1);

        bf16x8 afr[2][2];          // depth-2 A-fragment ring
        ALOAD1(cc, 0, afr[0]);
        ALOAD1(cc, 1, afr[1]);

        if (cc < 3) ISSUE(cc + 1);

        asm volatile("s_waitcnt lgkmcnt(0)" ::: "memory");
        __builtin_amdgcn_s_barrier();
        asm volatile("" ::: "memory");

        #pragma unroll
        for (int tap = 0; tap < 9; ++tap) {
            const int r = tap / 3, s = tap % 3;
            bf16x8 a0 = afr[tap & 1][0];
            bf16x8 a1 = afr[tap & 1][1];
            if (tap + 2 < 9) ALOAD1(cc, tap + 2, afr[tap & 1]);
            #pragma unroll
            for (int nt = 0; nt < 4; ++nt) {
                const int lcol = nt * 32 + l31 + s;
                const int gp   = hi ^ ((lcol >> 2) & 1);
                bf16x8 bv = *reinterpret_cast<const bf16x8*>(
                    &xs[cc & 1][wv + r][lcol][gp * 8]);
                acc[0][nt] = __builtin_amdgcn_mfma_f32_32x32x16_bf16(
                    a0, bv, acc[0][nt], 0, 0, 0);
                acc[1][nt] = __builtin_amdgcn_mfma_f32_32x32x16_bf16(
                    a1, bv, acc[1][nt], 0, 0, 0);
            }
        }
    }

    // epilogue: coalesced nontemporal stores (out is never re-read)
    float* ob = out + (size_t)n * KOUT * HW + (size_t)(h0 + wv) * WW_;
    #pragma unroll
    for (int mt = 0; mt < 2; ++mt)
        #pragma unroll
        for (int p = 0; p < 16; ++p) {
            const int ko = mt * 32 + (p & 3) + 8 * (p >> 2) + 4 * hi;
            #pragma unroll
            for (int nt = 0; nt < 4; ++nt)
                __builtin_nontemporal_store(acc[mt][nt][p],
                    &ob[(size_t)ko * HW + nt * 32 + l31]);
        }
}

extern "C" void kernel_launch(void* const* d_in, const int* in_sizes, int n_in,
                              void* d_out, int out_size, void* d_ws, size_t ws_size,
                              hipStream_t stream) {
    const float* x    = (const float*)d_in[0];
    const float* wgt  = (const float*)d_in[1];
    const float* bias = (const float*)d_in[2];
    float* out        = (float*)d_out;
    unsigned short* wpk = (unsigned short*)d_ws;  // 73728 B needed

    prepack<<<dim3(144), dim3(256), 0, stream>>>(wgt, wpk);
    conv_mfma<<<dim3(1024), dim3(256), 0, stream>>>(x, wpk, bias, out);
}